// Round 4
// baseline (182.603 us; speedup 1.0000x reference)
//
#include <hip/hip_runtime.h>
#include <hip/hip_bf16.h>
#include <math.h>

#define D_MODEL 512
#define N_HEADS 16
#define HEAD_DIM 32
#define T_SEQ 2048
#define B_SZ 2
#define NTOK (B_SZ * T_SEQ)        // 4096
#define QKV_DIM (3 * D_MODEL)      // 1536

typedef short short8 __attribute__((ext_vector_type(8)));
typedef float f32x4  __attribute__((ext_vector_type(4)));

__device__ __forceinline__ float bf2f(unsigned int u16) {
    union { unsigned int i; float f; } v;
    v.i = u16 << 16;
    return v.f;
}

__device__ __forceinline__ unsigned short f2bf(float f) {   // RNE
    union { float f; unsigned int i; } v;
    v.f = f;
    unsigned int lsb = (v.i >> 16) & 1u;
    v.i += 0x7fffu + lsb;
    return (unsigned short)(v.i >> 16);
}

__device__ __forceinline__ unsigned short f2bf_trunc(float f) {  // 1-op, f >= 0
    union { float f; unsigned int i; } v;
    v.f = f;
    return (unsigned short)(v.i >> 16);
}

__device__ __forceinline__ void gld_lds16(const void* g, void* l) {
    __builtin_amdgcn_global_load_lds(
        (const __attribute__((address_space(1))) void*)g,
        (__attribute__((address_space(3))) void*)l, 16, 0, 0);
}

// single fused fp32->bf16 convert for x | w_qkv | w_o (float4 granules)
#define N4_X   (NTOK * D_MODEL / 4)            // 524288
#define N4_WQ  (QKV_DIM * D_MODEL / 4)         // 196608
#define N4_WO  (D_MODEL * D_MODEL / 4)         // 65536
__global__ __launch_bounds__(256) void cvt_all(const float* __restrict__ x,
                                               const float* __restrict__ wq,
                                               const float* __restrict__ wo,
                                               unsigned short* __restrict__ xb,
                                               unsigned short* __restrict__ wqb,
                                               unsigned short* __restrict__ wob) {
    int i = blockIdx.x * 256 + threadIdx.x;
    const float* in;
    unsigned short* out;
    int k;
    if (i < N4_X)                { in = x;  out = xb;  k = i; }
    else if (i < N4_X + N4_WQ)   { in = wq; out = wqb; k = i - N4_X; }
    else if (i < N4_X + N4_WQ + N4_WO) { in = wo; out = wob; k = i - N4_X - N4_WQ; }
    else return;
    float4 v = ((const float4*)in)[k];
    ushort4 o;
    o.x = f2bf(v.x); o.y = f2bf(v.y); o.z = f2bf(v.z); o.w = f2bf(v.w);
    ((ushort4*)out)[k] = o;
}

// ---------------------------------------------------------------------------
// MT x 64 tile MFMA NT-GEMM (verified R0 structure, exact).
// ---------------------------------------------------------------------------
#define LOG2_10000_D16 0.8304820237218405f
#define QSCALE_LOG2 0.2550348788f   // (1/sqrt(32)) * log2(e)

template<int MT, int LDA, int LDC, bool OUT_BF16, bool ROPE>
__global__ __launch_bounds__(256) void gemm_nt(const unsigned short* __restrict__ A,
                                               const unsigned short* __restrict__ B,
                                               void* __restrict__ Cout,
                                               unsigned short* __restrict__ kb,
                                               unsigned short* __restrict__ vt) {
    __shared__ unsigned short Als[MT * 64];
    __shared__ unsigned short Bls[64 * 64];

    const int tid = threadIdx.x;
    const int m0 = blockIdx.y * MT;
    const int n0 = blockIdx.x * 64;

    const int wid  = tid >> 6;
    const int lane = tid & 63;
    const int c    = lane & 15;
    const int quad = lane >> 4;
    const int wm = (wid >> 1) * (MT / 2);
    const int wn = (wid & 1) * 32;
    const int MI = MT / 32;

    f32x4 acc[MI][2];
#pragma unroll
    for (int i = 0; i < MI; ++i)
#pragma unroll
        for (int j = 0; j < 2; ++j) acc[i][j] = (f32x4)0.f;

    const int srow = wid * 8 + (lane >> 3);
    const int schk = lane & 7;

    for (int k0 = 0; k0 < 512; k0 += 64) {
#pragma unroll
        for (int it = 0; it < MT / 32; ++it) {
            const unsigned short* g = A + (size_t)(m0 + it * 32 + srow) * LDA + k0 + schk * 8;
            gld_lds16(g, &Als[(it * 32 + srow) * 64 + schk * 8]);
        }
#pragma unroll
        for (int it = 0; it < 2; ++it) {
            const unsigned short* g = B + (size_t)(n0 + it * 32 + srow) * 512 + k0 + schk * 8;
            gld_lds16(g, &Bls[(it * 32 + srow) * 64 + schk * 8]);
        }
        __syncthreads();

#pragma unroll
        for (int kk = 0; kk < 2; ++kk) {
            short8 af[MI], bfr[2];
#pragma unroll
            for (int i = 0; i < MI; ++i)
                af[i] = *(const short8*)&Als[(wm + i * 16 + c) * 64 + kk * 32 + quad * 8];
#pragma unroll
            for (int j = 0; j < 2; ++j)
                bfr[j] = *(const short8*)&Bls[(wn + j * 16 + c) * 64 + kk * 32 + quad * 8];
#pragma unroll
            for (int i = 0; i < MI; ++i)
#pragma unroll
                for (int j = 0; j < 2; ++j)
                    acc[i][j] = __builtin_amdgcn_mfma_f32_16x16x32_bf16(af[i], bfr[j], acc[i][j], 0, 0, 0);
        }
        __syncthreads();
    }

    if (ROPE) {
        const int sec = n0 >> 9;     // 0 = Q, 1 = K, 2 = V
        if (sec == 0) {
            const float invf = exp2f(-LOG2_10000_D16 * (float)c);
#pragma unroll
            for (int i = 0; i < MI; ++i)
#pragma unroll
                for (int r = 0; r < 4; ++r) {
                    int t = (m0 + wm + i * 16 + quad * 4 + r) & (T_SEQ - 1);
                    float ss, cc;
                    sincosf((float)t * invf, &ss, &cc);
                    float e0 = acc[i][0][r], e1 = acc[i][1][r];
                    acc[i][0][r] = (e0 * cc - e1 * ss) * QSCALE_LOG2;
                    acc[i][1][r] = (e1 * cc + e0 * ss) * QSCALE_LOG2;
                }
            // falls through to generic bf16 writer -> qb (LDC = 512)
        } else if (sec == 1) {
            const float invf = exp2f(-LOG2_10000_D16 * (float)c);
            const int head = ((n0 - 512) + wn) >> 5;
#pragma unroll
            for (int i = 0; i < MI; ++i)
#pragma unroll
                for (int r = 0; r < 4; ++r) {
                    int mm = m0 + wm + i * 16 + quad * 4 + r;
                    int t = mm & (T_SEQ - 1);
                    float ss, cc;
                    sincosf((float)t * invf, &ss, &cc);
                    float e0 = acc[i][0][r], e1 = acc[i][1][r];
                    float k0v = e0 * cc - e1 * ss;     // d = c
                    float k1v = e1 * cc + e0 * ss;     // d = 16 + c
                    int bh = (mm >> 11) * 16 + head;
                    int s = (t & 3) ^ ((t >> 2) & 3);
                    unsigned short* row = kb + ((size_t)(bh * 2048 + t)) * 32;
                    row[((((c) >> 3) ^ s) << 3) + (c & 7)]        = f2bf(k0v);
                    row[((((16 + c) >> 3) ^ s) << 3) + (c & 7)]   = f2bf(k1v);
                }
            return;
        } else {
            // V -> vt[bh][d][t] with chunk swizzle; 4 acc rows = 4 consec t
#pragma unroll
            for (int i = 0; i < MI; ++i)
#pragma unroll
                for (int j = 0; j < 2; ++j) {
                    int nl = n0 - 1024 + wn + j * 16;
                    int head = nl >> 5;
                    int d = (nl & 16) + c;
                    int mm = m0 + wm + i * 16 + quad * 4;
                    int bI = mm >> 11;
                    int pos = mm & (T_SEQ - 1);
                    int phys = ((pos >> 3) & 7) ^ (d & 7);
                    size_t base = ((size_t)((bI * 16 + head) * 32 + d)) * 2048
                                  + (pos & ~63) + (phys << 3) + (pos & 7);
                    ushort4 st;
                    st.x = f2bf(acc[i][j][0]); st.y = f2bf(acc[i][j][1]);
                    st.z = f2bf(acc[i][j][2]); st.w = f2bf(acc[i][j][3]);
                    *(ushort4*)(vt + base) = st;
                }
            return;
        }
    }

    if (OUT_BF16) {
        unsigned short* Cb = (unsigned short*)Cout;
#pragma unroll
        for (int i = 0; i < MI; ++i)
#pragma unroll
            for (int j = 0; j < 2; ++j)
#pragma unroll
                for (int r = 0; r < 4; ++r) {
                    int mm = m0 + wm + i * 16 + quad * 4 + r;
                    int nn = n0 + wn + j * 16 + c;
                    Cb[(size_t)mm * LDC + nn] = f2bf(acc[i][j][r]);
                }
    } else {
        float* Cf = (float*)Cout;
#pragma unroll
        for (int i = 0; i < MI; ++i)
#pragma unroll
            for (int j = 0; j < 2; ++j)
#pragma unroll
                for (int r = 0; r < 4; ++r) {
                    int mm = m0 + wm + i * 16 + quad * 4 + r;
                    int nn = n0 + wn + j * 16 + c;
                    Cf[(size_t)mm * LDC + nn] = acc[i][j][r];
                }
    }
}

// ---------------------------------------------------------------------------
// Flash attention — EXACT R0 (best-measured) structure, with one change:
// output goes to a separate buffer `ob` (not in-place over qb), making the
// kernel idempotent. MEASUREMENT ROUND: launched 3x to time it differentially
// (T_flash = (dur - 121.6)/2).
// ---------------------------------------------------------------------------
__global__ __launch_bounds__(256) void flash_attn(const unsigned short* __restrict__ qb,
                                                  const unsigned short* __restrict__ kb,
                                                  const unsigned short* __restrict__ vt,
                                                  unsigned short* __restrict__ ob) {
    __shared__ unsigned short KtL[64 * 32];   // [key][32 halves, chunk-swizzled]
    __shared__ unsigned short VtL[32 * 64];   // [d][64 halves, chunk-swizzled]
    __shared__ unsigned short Pl[4 * 16 * 64];

    const int idx   = blockIdx.x;             // 0..1023
    const int qtile = 31 - (idx >> 5);        // globally heavy first
    const int bh    = idx & 31;
    const int b = bh >> 4, h = bh & 15;
    const int tid  = threadIdx.x;
    const int wid  = tid >> 6;
    const int lane = tid & 63;
    const int c    = lane & 15;
    const int quad = lane >> 4;

    const int q0w = qtile * 64 + wid * 16;
    const int sK = (c & 3) ^ ((c >> 2) & 3);   // K chunk swizzle (key = j*16+c)
    const int sP = c & 7;                      // P/V chunk swizzle

    short8 qf = *(const short8*)(qb + ((size_t)(b * T_SEQ + q0w + c)) * 512 + h * HEAD_DIM + quad * 8);

    f32x4 accO[2];
    accO[0] = (f32x4)0.f; accO[1] = (f32x4)0.f;
    float l_r[4] = {0.f, 0.f, 0.f, 0.f};

    unsigned short* plw = &Pl[wid * 16 * 64];

    // staging coordinates (match verified gld_lds16 lane-contiguous mapping)
    const int krow = tid >> 2, kch = tid & 3;
    const int vd   = tid >> 3, vch = tid & 7;
    const unsigned short* kbase = kb + (size_t)bh * 2048 * 32 + (size_t)krow * 32 + kch * 8;
    const unsigned short* vbase = vt + ((size_t)(bh * 32 + vd)) * 2048 + vch * 8;

    uint4 kreg = *(const uint4*)(kbase);
    uint4 vreg = *(const uint4*)(vbase);

    const int nkt = qtile + 1;
    for (int kt = 0; kt < nkt; ++kt) {
        __syncthreads();                    // prior compute done reading LDS
        *(uint4*)&KtL[tid * 8] = kreg;      // regs landed ~1 full iter ago
        *(uint4*)&VtL[tid * 8] = vreg;
        __syncthreads();                    // staging visible

        if (kt + 1 < nkt) {                 // prefetch next tile into regs
            kreg = *(const uint4*)(kbase + (size_t)(kt + 1) * 64 * 32);
            vreg = *(const uint4*)(vbase + (kt + 1) * 64);
        }

        // --- S = Q.K^T ---
        f32x4 sv[4];
#pragma unroll
        for (int j = 0; j < 4; ++j) {
            short8 kf = *(const short8*)&KtL[(j * 16 + c) * 32 + ((quad ^ sK) << 3)];
            f32x4 z = (f32x4)0.f;
            sv[j] = __builtin_amdgcn_mfma_f32_16x16x32_bf16(qf, kf, z, 0, 0, 0);
        }

        if (kt == qtile) {
#pragma unroll
            for (int j = 0; j < 4; ++j)
#pragma unroll
                for (int r = 0; r < 4; ++r)
                    if (j * 16 + c > wid * 16 + quad * 4 + r) sv[j][r] = -30000.f;
        }

        // --- static softmax base-2; P -> LDS (chunk-swizzled) ---
#pragma unroll
        for (int j = 0; j < 4; ++j)
#pragma unroll
            for (int r = 0; r < 4; ++r) {
                float p = exp2f(sv[j][r]);
                l_r[r] += p;
                int row = quad * 4 + r;
                plw[row * 64 + (((j * 2 + (c >> 3)) ^ (row & 7)) << 3) + (c & 7)] = f2bf_trunc(p);
            }

        // --- PV ---
#pragma unroll
        for (int kk = 0; kk < 2; ++kk) {
            short8 pf = *(const short8*)&plw[c * 64 + (((kk * 4 + quad) ^ sP) << 3)];
#pragma unroll
            for (int ns = 0; ns < 2; ++ns) {
                short8 vf = *(const short8*)&VtL[(ns * 16 + c) * 64 + (((kk * 4 + quad) ^ sP) << 3)];
                accO[ns] = __builtin_amdgcn_mfma_f32_16x16x32_bf16(pf, vf, accO[ns], 0, 0, 0);
            }
        }
    }

    // --- epilogue: reduce l over c-lanes, normalize, write to ob ---
#pragma unroll
    for (int r = 0; r < 4; ++r) {
        float lr = l_r[r];
        lr += __shfl_xor(lr, 1);
        lr += __shfl_xor(lr, 2);
        lr += __shfl_xor(lr, 4);
        lr += __shfl_xor(lr, 8);
        float inv = 1.f / lr;
        int qg = q0w + quad * 4 + r;
        unsigned short* op = ob + ((size_t)(b * T_SEQ + qg)) * 512 + h * HEAD_DIM;
#pragma unroll
        for (int ns = 0; ns < 2; ++ns)
            op[ns * 16 + c] = f2bf(accO[ns][r] * inv);
    }
}

extern "C" void kernel_launch(void* const* d_in, const int* in_sizes, int n_in,
                              void* d_out, int out_size, void* d_ws, size_t ws_size,
                              hipStream_t stream) {
    const float* x     = (const float*)d_in[0];
    const float* w_qkv = (const float*)d_in[1];
    const float* w_o   = (const float*)d_in[2];
    float* out = (float*)d_out;

    // workspace (ushorts): qb 4MB | kb 4 | vt 4 | xb 4 | wqb 1.5 | wob 0.5 | ob 4
    unsigned short* qb  = (unsigned short*)d_ws;
    unsigned short* kb  = qb  + (size_t)NTOK * D_MODEL;
    unsigned short* vt  = kb  + (size_t)32 * 2048 * 32;
    unsigned short* xb  = vt  + (size_t)32 * 32 * 2048;
    unsigned short* wqb = xb  + (size_t)NTOK * D_MODEL;
    unsigned short* wob = wqb + (size_t)QKV_DIM * D_MODEL;
    unsigned short* ob  = wob + (size_t)D_MODEL * D_MODEL;

    {
        int total = N4_X + N4_WQ + N4_WO;
        cvt_all<<<(total + 255) / 256, 256, 0, stream>>>(x, w_qkv, w_o, xb, wqb, wob);
    }
    // QKV projection + fused RoPE/scale; Q->qb, K->kb (swizzled), V->vt (swizzled)
    {
        dim3 grid(QKV_DIM / 64, NTOK / 128);   // (24, 32) = 768 blocks
        gemm_nt<128, D_MODEL, D_MODEL, true, true><<<grid, 256, 0, stream>>>(xb, wqb, qb, kb, vt);
    }
    // Flash: MEASUREMENT — launched 3x (idempotent; T_flash = (dur-121.6)/2)
    {
        flash_attn<<<1024, 256, 0, stream>>>(qb, kb, vt, ob);
        flash_attn<<<1024, 256, 0, stream>>>(qb, kb, vt, ob);
        flash_attn<<<1024, 256, 0, stream>>>(qb, kb, vt, ob);
    }
    // Output projection (A = attn in ob, lda 512) -> fp32 out
    {
        dim3 grid(D_MODEL / 64, NTOK / 64);   // (8, 64) = 512 blocks
        gemm_nt<64, D_MODEL, D_MODEL, false, false><<<grid, 256, 0, stream>>>(ob, wob, out, nullptr, nullptr);
    }
}

// Round 5
// 133.032 us; speedup vs baseline: 1.3726x; 1.3726x over previous
//
#include <hip/hip_runtime.h>
#include <hip/hip_bf16.h>
#include <math.h>

#define D_MODEL 512
#define N_HEADS 16
#define HEAD_DIM 32
#define T_SEQ 2048
#define B_SZ 2
#define NTOK (B_SZ * T_SEQ)        // 4096
#define QKV_DIM (3 * D_MODEL)      // 1536

typedef short short8 __attribute__((ext_vector_type(8)));
typedef float f32x4  __attribute__((ext_vector_type(4)));

__device__ __forceinline__ float bf2f(unsigned int u16) {
    union { unsigned int i; float f; } v;
    v.i = u16 << 16;
    return v.f;
}

__device__ __forceinline__ unsigned short f2bf(float f) {   // RNE
    union { float f; unsigned int i; } v;
    v.f = f;
    unsigned int lsb = (v.i >> 16) & 1u;
    v.i += 0x7fffu + lsb;
    return (unsigned short)(v.i >> 16);
}

__device__ __forceinline__ unsigned short f2bf_trunc(float f) {  // 1-op, f >= 0
    union { float f; unsigned int i; } v;
    v.f = f;
    return (unsigned short)(v.i >> 16);
}

__device__ __forceinline__ void gld_lds16(const void* g, void* l) {
    __builtin_amdgcn_global_load_lds(
        (const __attribute__((address_space(1))) void*)g,
        (__attribute__((address_space(3))) void*)l, 16, 0, 0);
}

// single fused fp32->bf16 convert for x | w_qkv | w_o (float4 granules)
#define N4_X   (NTOK * D_MODEL / 4)            // 524288
#define N4_WQ  (QKV_DIM * D_MODEL / 4)         // 196608
#define N4_WO  (D_MODEL * D_MODEL / 4)         // 65536
__global__ __launch_bounds__(256) void cvt_all(const float* __restrict__ x,
                                               const float* __restrict__ wq,
                                               const float* __restrict__ wo,
                                               unsigned short* __restrict__ xb,
                                               unsigned short* __restrict__ wqb,
                                               unsigned short* __restrict__ wob) {
    int i = blockIdx.x * 256 + threadIdx.x;
    const float* in;
    unsigned short* out;
    int k;
    if (i < N4_X)                { in = x;  out = xb;  k = i; }
    else if (i < N4_X + N4_WQ)   { in = wq; out = wqb; k = i - N4_X; }
    else if (i < N4_X + N4_WQ + N4_WO) { in = wo; out = wob; k = i - N4_X - N4_WQ; }
    else return;
    float4 v = ((const float4*)in)[k];
    ushort4 o;
    o.x = f2bf(v.x); o.y = f2bf(v.y); o.z = f2bf(v.z); o.w = f2bf(v.w);
    ((ushort4*)out)[k] = o;
}

// ---------------------------------------------------------------------------
// MT x 64 tile MFMA NT-GEMM (verified R0 structure, exact).
// ---------------------------------------------------------------------------
#define LOG2_10000_D16 0.8304820237218405f
#define QSCALE_LOG2 0.2550348788f   // (1/sqrt(32)) * log2(e)

template<int MT, int LDA, int LDC, bool OUT_BF16, bool ROPE>
__global__ __launch_bounds__(256) void gemm_nt(const unsigned short* __restrict__ A,
                                               const unsigned short* __restrict__ B,
                                               void* __restrict__ Cout,
                                               unsigned short* __restrict__ kb,
                                               unsigned short* __restrict__ vt) {
    __shared__ unsigned short Als[MT * 64];
    __shared__ unsigned short Bls[64 * 64];

    const int tid = threadIdx.x;
    const int m0 = blockIdx.y * MT;
    const int n0 = blockIdx.x * 64;

    const int wid  = tid >> 6;
    const int lane = tid & 63;
    const int c    = lane & 15;
    const int quad = lane >> 4;
    const int wm = (wid >> 1) * (MT / 2);
    const int wn = (wid & 1) * 32;
    const int MI = MT / 32;

    f32x4 acc[MI][2];
#pragma unroll
    for (int i = 0; i < MI; ++i)
#pragma unroll
        for (int j = 0; j < 2; ++j) acc[i][j] = (f32x4)0.f;

    const int srow = wid * 8 + (lane >> 3);
    const int schk = lane & 7;

    for (int k0 = 0; k0 < 512; k0 += 64) {
#pragma unroll
        for (int it = 0; it < MT / 32; ++it) {
            const unsigned short* g = A + (size_t)(m0 + it * 32 + srow) * LDA + k0 + schk * 8;
            gld_lds16(g, &Als[(it * 32 + srow) * 64 + schk * 8]);
        }
#pragma unroll
        for (int it = 0; it < 2; ++it) {
            const unsigned short* g = B + (size_t)(n0 + it * 32 + srow) * 512 + k0 + schk * 8;
            gld_lds16(g, &Bls[(it * 32 + srow) * 64 + schk * 8]);
        }
        __syncthreads();

#pragma unroll
        for (int kk = 0; kk < 2; ++kk) {
            short8 af[MI], bfr[2];
#pragma unroll
            for (int i = 0; i < MI; ++i)
                af[i] = *(const short8*)&Als[(wm + i * 16 + c) * 64 + kk * 32 + quad * 8];
#pragma unroll
            for (int j = 0; j < 2; ++j)
                bfr[j] = *(const short8*)&Bls[(wn + j * 16 + c) * 64 + kk * 32 + quad * 8];
#pragma unroll
            for (int i = 0; i < MI; ++i)
#pragma unroll
                for (int j = 0; j < 2; ++j)
                    acc[i][j] = __builtin_amdgcn_mfma_f32_16x16x32_bf16(af[i], bfr[j], acc[i][j], 0, 0, 0);
        }
        __syncthreads();
    }

    if (ROPE) {
        const int sec = n0 >> 9;     // 0 = Q, 1 = K, 2 = V
        if (sec == 0) {
            const float invf = exp2f(-LOG2_10000_D16 * (float)c);
#pragma unroll
            for (int i = 0; i < MI; ++i)
#pragma unroll
                for (int r = 0; r < 4; ++r) {
                    int t = (m0 + wm + i * 16 + quad * 4 + r) & (T_SEQ - 1);
                    float ss, cc;
                    sincosf((float)t * invf, &ss, &cc);
                    float e0 = acc[i][0][r], e1 = acc[i][1][r];
                    acc[i][0][r] = (e0 * cc - e1 * ss) * QSCALE_LOG2;
                    acc[i][1][r] = (e1 * cc + e0 * ss) * QSCALE_LOG2;
                }
            // falls through to generic bf16 writer -> qb (LDC = 512)
        } else if (sec == 1) {
            const float invf = exp2f(-LOG2_10000_D16 * (float)c);
            const int head = ((n0 - 512) + wn) >> 5;
#pragma unroll
            for (int i = 0; i < MI; ++i)
#pragma unroll
                for (int r = 0; r < 4; ++r) {
                    int mm = m0 + wm + i * 16 + quad * 4 + r;
                    int t = mm & (T_SEQ - 1);
                    float ss, cc;
                    sincosf((float)t * invf, &ss, &cc);
                    float e0 = acc[i][0][r], e1 = acc[i][1][r];
                    float k0v = e0 * cc - e1 * ss;     // d = c
                    float k1v = e1 * cc + e0 * ss;     // d = 16 + c
                    int bh = (mm >> 11) * 16 + head;
                    int s = (t & 3) ^ ((t >> 2) & 3);
                    unsigned short* row = kb + ((size_t)(bh * 2048 + t)) * 32;
                    row[((((c) >> 3) ^ s) << 3) + (c & 7)]        = f2bf(k0v);
                    row[((((16 + c) >> 3) ^ s) << 3) + (c & 7)]   = f2bf(k1v);
                }
            return;
        } else {
            // V -> vt[bh][d][t] with chunk swizzle; 4 acc rows = 4 consec t
#pragma unroll
            for (int i = 0; i < MI; ++i)
#pragma unroll
                for (int j = 0; j < 2; ++j) {
                    int nl = n0 - 1024 + wn + j * 16;
                    int head = nl >> 5;
                    int d = (nl & 16) + c;
                    int mm = m0 + wm + i * 16 + quad * 4;
                    int bI = mm >> 11;
                    int pos = mm & (T_SEQ - 1);
                    int phys = ((pos >> 3) & 7) ^ (d & 7);
                    size_t base = ((size_t)((bI * 16 + head) * 32 + d)) * 2048
                                  + (pos & ~63) + (phys << 3) + (pos & 7);
                    ushort4 st;
                    st.x = f2bf(acc[i][j][0]); st.y = f2bf(acc[i][j][1]);
                    st.z = f2bf(acc[i][j][2]); st.w = f2bf(acc[i][j][3]);
                    *(ushort4*)(vt + base) = st;
                }
            return;
        }
    }

    if (OUT_BF16) {
        unsigned short* Cb = (unsigned short*)Cout;
#pragma unroll
        for (int i = 0; i < MI; ++i)
#pragma unroll
            for (int j = 0; j < 2; ++j)
#pragma unroll
                for (int r = 0; r < 4; ++r) {
                    int mm = m0 + wm + i * 16 + quad * 4 + r;
                    int nn = n0 + wn + j * 16 + c;
                    Cb[(size_t)mm * LDC + nn] = f2bf(acc[i][j][r]);
                }
    } else {
        float* Cf = (float*)Cout;
#pragma unroll
        for (int i = 0; i < MI; ++i)
#pragma unroll
            for (int j = 0; j < 2; ++j)
#pragma unroll
                for (int r = 0; r < 4; ++r) {
                    int mm = m0 + wm + i * 16 + quad * 4 + r;
                    int nn = n0 + wn + j * 16 + c;
                    Cf[(size_t)mm * LDC + nn] = acc[i][j][r];
                }
    }
}

// ---------------------------------------------------------------------------
// Flash attention v8: Q-tile 128 rows (2 row-fragments per wave).
//  * Per kt-iteration: 16 MFMA (was 8) with 2x fragment-level ILP on the
//    same serial chain; block-iterations 16896 -> 8704; K/V staging traffic
//    and barrier count per unit work halved.
//  * Grid 512 = 16 qtiles x 32 bh, globally heavy-first (qtile 15 first).
//  * Masking on the last TWO 64-key tiles via global index compare.
//  * R0's verified 2-barrier single-buffer loop + register prefetch.
//  * All LDS swizzles identical (P-row swizzle invariant: row&7 == c&7 on
//    the PV read side, unchanged with row = i*16 + c).
// ---------------------------------------------------------------------------
__global__ __launch_bounds__(256) void flash_attn(const unsigned short* __restrict__ qb,
                                                  const unsigned short* __restrict__ kb,
                                                  const unsigned short* __restrict__ vt,
                                                  unsigned short* __restrict__ ob) {
    __shared__ unsigned short KtL[64 * 32];    // [key][32 halves, chunk-swizzled]
    __shared__ unsigned short VtL[32 * 64];    // [d][64 halves, chunk-swizzled]
    __shared__ unsigned short Pl[4 * 32 * 64]; // per-wave 32 rows x 64 keys

    const int idx   = blockIdx.x;             // 0..511
    const int qtile = 15 - (idx >> 5);        // globally heavy first (128-row tiles)
    const int bh    = idx & 31;
    const int b = bh >> 4, h = bh & 15;
    const int tid  = threadIdx.x;
    const int wid  = tid >> 6;
    const int lane = tid & 63;
    const int c    = lane & 15;
    const int quad = lane >> 4;

    const int q0w = qtile * 128 + wid * 32;    // wave's first q-row
    const int sK = (c & 3) ^ ((c >> 2) & 3);   // K chunk swizzle (key = j*16+c)
    const int sP = c & 7;                      // P/V chunk swizzle

    short8 qf[2];
#pragma unroll
    for (int i = 0; i < 2; ++i)
        qf[i] = *(const short8*)(qb + ((size_t)(b * T_SEQ + q0w + i * 16 + c)) * 512
                                 + h * HEAD_DIM + quad * 8);

    f32x4 accO[2][2];
#pragma unroll
    for (int i = 0; i < 2; ++i) { accO[i][0] = (f32x4)0.f; accO[i][1] = (f32x4)0.f; }
    float l_r[2][4] = {{0.f,0.f,0.f,0.f},{0.f,0.f,0.f,0.f}};

    unsigned short* plw = &Pl[wid * 32 * 64];

    // staging coordinates (verified gld_lds16-compatible lane-contiguous mapping)
    const int krow = tid >> 2, kch = tid & 3;
    const int vd   = tid >> 3, vch = tid & 7;
    const unsigned short* kbase = kb + (size_t)bh * 2048 * 32 + (size_t)krow * 32 + kch * 8;
    const unsigned short* vbase = vt + ((size_t)(bh * 32 + vd)) * 2048 + vch * 8;

    uint4 kreg = *(const uint4*)(kbase);
    uint4 vreg = *(const uint4*)(vbase);

    const int nkt = (qtile + 1) * 2;           // 64-key tiles
    for (int kt = 0; kt < nkt; ++kt) {
        __syncthreads();                    // prior compute done reading LDS
        *(uint4*)&KtL[tid * 8] = kreg;      // regs landed ~1 full iter ago
        *(uint4*)&VtL[tid * 8] = vreg;
        __syncthreads();                    // staging visible

        if (kt + 1 < nkt) {                 // prefetch next tile into regs
            kreg = *(const uint4*)(kbase + (size_t)(kt + 1) * 64 * 32);
            vreg = *(const uint4*)(vbase + (kt + 1) * 64);
        }

        // --- S = Q.K^T (2 row-fragments share each K fragment) ---
        f32x4 sv[2][4];
#pragma unroll
        for (int j = 0; j < 4; ++j) {
            short8 kf = *(const short8*)&KtL[(j * 16 + c) * 32 + ((quad ^ sK) << 3)];
#pragma unroll
            for (int i = 0; i < 2; ++i) {
                f32x4 z = (f32x4)0.f;
                sv[i][j] = __builtin_amdgcn_mfma_f32_16x16x32_bf16(qf[i], kf, z, 0, 0, 0);
            }
        }

        if (kt >= nkt - 2) {               // causal mask on the two diagonal tiles
            const int keyb = kt * 64;
#pragma unroll
            for (int i = 0; i < 2; ++i)
#pragma unroll
                for (int j = 0; j < 4; ++j)
#pragma unroll
                    for (int r = 0; r < 4; ++r)
                        if (keyb + j * 16 + c > q0w + i * 16 + quad * 4 + r)
                            sv[i][j][r] = -30000.f;
        }

        // --- static softmax base-2; P -> LDS (chunk-swizzled, 32 rows/wave) ---
#pragma unroll
        for (int i = 0; i < 2; ++i)
#pragma unroll
            for (int j = 0; j < 4; ++j)
#pragma unroll
                for (int r = 0; r < 4; ++r) {
                    float p = exp2f(sv[i][j][r]);
                    l_r[i][r] += p;
                    int row = i * 16 + quad * 4 + r;
                    plw[row * 64 + (((j * 2 + (c >> 3)) ^ (row & 7)) << 3) + (c & 7)] = f2bf_trunc(p);
                }

        // --- PV ---
#pragma unroll
        for (int kk = 0; kk < 2; ++kk) {
            short8 pf[2];
#pragma unroll
            for (int i = 0; i < 2; ++i)
                pf[i] = *(const short8*)&plw[(i * 16 + c) * 64 + (((kk * 4 + quad) ^ sP) << 3)];
#pragma unroll
            for (int ns = 0; ns < 2; ++ns) {
                short8 vf = *(const short8*)&VtL[(ns * 16 + c) * 64 + (((kk * 4 + quad) ^ sP) << 3)];
#pragma unroll
                for (int i = 0; i < 2; ++i)
                    accO[i][ns] = __builtin_amdgcn_mfma_f32_16x16x32_bf16(pf[i], vf, accO[i][ns], 0, 0, 0);
            }
        }
    }

    // --- epilogue: reduce l over c-lanes, normalize, write to ob ---
#pragma unroll
    for (int i = 0; i < 2; ++i)
#pragma unroll
        for (int r = 0; r < 4; ++r) {
            float lr = l_r[i][r];
            lr += __shfl_xor(lr, 1);
            lr += __shfl_xor(lr, 2);
            lr += __shfl_xor(lr, 4);
            lr += __shfl_xor(lr, 8);
            float inv = 1.f / lr;
            int qg = q0w + i * 16 + quad * 4 + r;
            unsigned short* op = ob + ((size_t)(b * T_SEQ + qg)) * 512 + h * HEAD_DIM;
#pragma unroll
            for (int ns = 0; ns < 2; ++ns)
                op[ns * 16 + c] = f2bf(accO[i][ns][r] * inv);
        }
}

extern "C" void kernel_launch(void* const* d_in, const int* in_sizes, int n_in,
                              void* d_out, int out_size, void* d_ws, size_t ws_size,
                              hipStream_t stream) {
    const float* x     = (const float*)d_in[0];
    const float* w_qkv = (const float*)d_in[1];
    const float* w_o   = (const float*)d_in[2];
    float* out = (float*)d_out;

    // workspace (ushorts): qb 4MB | kb 4 | vt 4 | xb 4 | wqb 1.5 | wob 0.5 | ob 4
    unsigned short* qb  = (unsigned short*)d_ws;
    unsigned short* kb  = qb  + (size_t)NTOK * D_MODEL;
    unsigned short* vt  = kb  + (size_t)32 * 2048 * 32;
    unsigned short* xb  = vt  + (size_t)32 * 32 * 2048;
    unsigned short* wqb = xb  + (size_t)NTOK * D_MODEL;
    unsigned short* wob = wqb + (size_t)QKV_DIM * D_MODEL;
    unsigned short* ob  = wob + (size_t)D_MODEL * D_MODEL;

    {
        int total = N4_X + N4_WQ + N4_WO;
        cvt_all<<<(total + 255) / 256, 256, 0, stream>>>(x, w_qkv, w_o, xb, wqb, wob);
    }
    // QKV projection + fused RoPE/scale; Q->qb, K->kb (swizzled), V->vt (swizzled)
    {
        dim3 grid(QKV_DIM / 64, NTOK / 128);   // (24, 32) = 768 blocks
        gemm_nt<128, D_MODEL, D_MODEL, true, true><<<grid, 256, 0, stream>>>(xb, wqb, qb, kb, vt);
    }
    // Flash: 512 blocks (128-row q-tiles), globally heavy-first
    {
        flash_attn<<<512, 256, 0, stream>>>(qb, kb, vt, ob);
    }
    // Output projection (A = attn in ob, lda 512) -> fp32 out
    {
        dim3 grid(D_MODEL / 64, NTOK / 64);   // (8, 64) = 512 blocks
        gemm_nt<64, D_MODEL, D_MODEL, false, false><<<grid, 256, 0, stream>>>(ob, wob, out, nullptr, nullptr);
    }
}

// Round 6
// 129.584 us; speedup vs baseline: 1.4091x; 1.0266x over previous
//
#include <hip/hip_runtime.h>
#include <hip/hip_bf16.h>
#include <math.h>

#define D_MODEL 512
#define N_HEADS 16
#define HEAD_DIM 32
#define T_SEQ 2048
#define B_SZ 2
#define NTOK (B_SZ * T_SEQ)        // 4096
#define QKV_DIM (3 * D_MODEL)      // 1536

typedef short short8 __attribute__((ext_vector_type(8)));
typedef float f32x4  __attribute__((ext_vector_type(4)));

__device__ __forceinline__ float bf2f(unsigned int u16) {
    union { unsigned int i; float f; } v;
    v.i = u16 << 16;
    return v.f;
}

__device__ __forceinline__ unsigned short f2bf(float f) {   // RNE
    union { float f; unsigned int i; } v;
    v.f = f;
    unsigned int lsb = (v.i >> 16) & 1u;
    v.i += 0x7fffu + lsb;
    return (unsigned short)(v.i >> 16);
}

__device__ __forceinline__ unsigned short f2bf_trunc(float f) {  // 1-op, f >= 0
    union { float f; unsigned int i; } v;
    v.f = f;
    return (unsigned short)(v.i >> 16);
}

__device__ __forceinline__ void gld_lds16(const void* g, void* l) {
    __builtin_amdgcn_global_load_lds(
        (const __attribute__((address_space(1))) void*)g,
        (__attribute__((address_space(3))) void*)l, 16, 0, 0);
}

// single fused fp32->bf16 convert for x | w_qkv | w_o (float4 granules)
#define N4_X   (NTOK * D_MODEL / 4)            // 524288
#define N4_WQ  (QKV_DIM * D_MODEL / 4)         // 196608
#define N4_WO  (D_MODEL * D_MODEL / 4)         // 65536
__global__ __launch_bounds__(256) void cvt_all(const float* __restrict__ x,
                                               const float* __restrict__ wq,
                                               const float* __restrict__ wo,
                                               unsigned short* __restrict__ xb,
                                               unsigned short* __restrict__ wqb,
                                               unsigned short* __restrict__ wob) {
    int i = blockIdx.x * 256 + threadIdx.x;
    const float* in;
    unsigned short* out;
    int k;
    if (i < N4_X)                { in = x;  out = xb;  k = i; }
    else if (i < N4_X + N4_WQ)   { in = wq; out = wqb; k = i - N4_X; }
    else if (i < N4_X + N4_WQ + N4_WO) { in = wo; out = wob; k = i - N4_X - N4_WQ; }
    else return;
    float4 v = ((const float4*)in)[k];
    ushort4 o;
    o.x = f2bf(v.x); o.y = f2bf(v.y); o.z = f2bf(v.z); o.w = f2bf(v.w);
    ((ushort4*)out)[k] = o;
}

// ---------------------------------------------------------------------------
// MT x 64 tile MFMA NT-GEMM (verified R0 structure, exact).
// ---------------------------------------------------------------------------
#define LOG2_10000_D16 0.8304820237218405f
#define QSCALE_LOG2 0.2550348788f   // (1/sqrt(32)) * log2(e)

template<int MT, int LDA, int LDC, bool OUT_BF16, bool ROPE>
__global__ __launch_bounds__(256) void gemm_nt(const unsigned short* __restrict__ A,
                                               const unsigned short* __restrict__ B,
                                               void* __restrict__ Cout,
                                               unsigned short* __restrict__ kb,
                                               unsigned short* __restrict__ vt) {
    __shared__ unsigned short Als[MT * 64];
    __shared__ unsigned short Bls[64 * 64];

    const int tid = threadIdx.x;
    const int m0 = blockIdx.y * MT;
    const int n0 = blockIdx.x * 64;

    const int wid  = tid >> 6;
    const int lane = tid & 63;
    const int c    = lane & 15;
    const int quad = lane >> 4;
    const int wm = (wid >> 1) * (MT / 2);
    const int wn = (wid & 1) * 32;
    const int MI = MT / 32;

    f32x4 acc[MI][2];
#pragma unroll
    for (int i = 0; i < MI; ++i)
#pragma unroll
        for (int j = 0; j < 2; ++j) acc[i][j] = (f32x4)0.f;

    const int srow = wid * 8 + (lane >> 3);
    const int schk = lane & 7;

    for (int k0 = 0; k0 < 512; k0 += 64) {
#pragma unroll
        for (int it = 0; it < MT / 32; ++it) {
            const unsigned short* g = A + (size_t)(m0 + it * 32 + srow) * LDA + k0 + schk * 8;
            gld_lds16(g, &Als[(it * 32 + srow) * 64 + schk * 8]);
        }
#pragma unroll
        for (int it = 0; it < 2; ++it) {
            const unsigned short* g = B + (size_t)(n0 + it * 32 + srow) * 512 + k0 + schk * 8;
            gld_lds16(g, &Bls[(it * 32 + srow) * 64 + schk * 8]);
        }
        __syncthreads();

#pragma unroll
        for (int kk = 0; kk < 2; ++kk) {
            short8 af[MI], bfr[2];
#pragma unroll
            for (int i = 0; i < MI; ++i)
                af[i] = *(const short8*)&Als[(wm + i * 16 + c) * 64 + kk * 32 + quad * 8];
#pragma unroll
            for (int j = 0; j < 2; ++j)
                bfr[j] = *(const short8*)&Bls[(wn + j * 16 + c) * 64 + kk * 32 + quad * 8];
#pragma unroll
            for (int i = 0; i < MI; ++i)
#pragma unroll
                for (int j = 0; j < 2; ++j)
                    acc[i][j] = __builtin_amdgcn_mfma_f32_16x16x32_bf16(af[i], bfr[j], acc[i][j], 0, 0, 0);
        }
        __syncthreads();
    }

    if (ROPE) {
        const int sec = n0 >> 9;     // 0 = Q, 1 = K, 2 = V
        if (sec == 0) {
            const float invf = exp2f(-LOG2_10000_D16 * (float)c);
#pragma unroll
            for (int i = 0; i < MI; ++i)
#pragma unroll
                for (int r = 0; r < 4; ++r) {
                    int t = (m0 + wm + i * 16 + quad * 4 + r) & (T_SEQ - 1);
                    float ss, cc;
                    sincosf((float)t * invf, &ss, &cc);
                    float e0 = acc[i][0][r], e1 = acc[i][1][r];
                    acc[i][0][r] = (e0 * cc - e1 * ss) * QSCALE_LOG2;
                    acc[i][1][r] = (e1 * cc + e0 * ss) * QSCALE_LOG2;
                }
            // falls through to generic bf16 writer -> qb (LDC = 512)
        } else if (sec == 1) {
            const float invf = exp2f(-LOG2_10000_D16 * (float)c);
            const int head = ((n0 - 512) + wn) >> 5;
#pragma unroll
            for (int i = 0; i < MI; ++i)
#pragma unroll
                for (int r = 0; r < 4; ++r) {
                    int mm = m0 + wm + i * 16 + quad * 4 + r;
                    int t = mm & (T_SEQ - 1);
                    float ss, cc;
                    sincosf((float)t * invf, &ss, &cc);
                    float e0 = acc[i][0][r], e1 = acc[i][1][r];
                    float k0v = e0 * cc - e1 * ss;     // d = c
                    float k1v = e1 * cc + e0 * ss;     // d = 16 + c
                    int bh = (mm >> 11) * 16 + head;
                    int s = (t & 3) ^ ((t >> 2) & 3);
                    unsigned short* row = kb + ((size_t)(bh * 2048 + t)) * 32;
                    row[((((c) >> 3) ^ s) << 3) + (c & 7)]        = f2bf(k0v);
                    row[((((16 + c) >> 3) ^ s) << 3) + (c & 7)]   = f2bf(k1v);
                }
            return;
        } else {
            // V -> vt[bh][d][t] with chunk swizzle; 4 acc rows = 4 consec t
#pragma unroll
            for (int i = 0; i < MI; ++i)
#pragma unroll
                for (int j = 0; j < 2; ++j) {
                    int nl = n0 - 1024 + wn + j * 16;
                    int head = nl >> 5;
                    int d = (nl & 16) + c;
                    int mm = m0 + wm + i * 16 + quad * 4;
                    int bI = mm >> 11;
                    int pos = mm & (T_SEQ - 1);
                    int phys = ((pos >> 3) & 7) ^ (d & 7);
                    size_t base = ((size_t)((bI * 16 + head) * 32 + d)) * 2048
                                  + (pos & ~63) + (phys << 3) + (pos & 7);
                    ushort4 st;
                    st.x = f2bf(acc[i][j][0]); st.y = f2bf(acc[i][j][1]);
                    st.z = f2bf(acc[i][j][2]); st.w = f2bf(acc[i][j][3]);
                    *(ushort4*)(vt + base) = st;
                }
            return;
        }
    }

    if (OUT_BF16) {
        unsigned short* Cb = (unsigned short*)Cout;
#pragma unroll
        for (int i = 0; i < MI; ++i)
#pragma unroll
            for (int j = 0; j < 2; ++j)
#pragma unroll
                for (int r = 0; r < 4; ++r) {
                    int mm = m0 + wm + i * 16 + quad * 4 + r;
                    int nn = n0 + wn + j * 16 + c;
                    Cb[(size_t)mm * LDC + nn] = f2bf(acc[i][j][r]);
                }
    } else {
        float* Cf = (float*)Cout;
#pragma unroll
        for (int i = 0; i < MI; ++i)
#pragma unroll
            for (int j = 0; j < 2; ++j)
#pragma unroll
                for (int r = 0; r < 4; ++r) {
                    int mm = m0 + wm + i * 16 + quad * 4 + r;
                    int nn = n0 + wn + j * 16 + c;
                    Cf[(size_t)mm * LDC + nn] = acc[i][j][r];
                }
    }
}

// ---------------------------------------------------------------------------
// Flash attention v9: split-K x4 (chunks of <=8 K-tiles), R0 inner loop.
//  Chain-bound diagnosis (R5 counters: Occ 12%, MfmaUtil 7%, VALU 39%):
//  makespan = longest chain (32 iters) x ~0.95us. Chunking the K-range into
//  <=8-tile pieces cuts max chain to 8 and raises grid to 2560 blocks.
//  Static softmax (p = exp2(s), no running max) => partials are associative.
//  Every chunk writes unnormalized f32 partials (pO, pL); combine sums <=4.
//  Per-bh chunk enumeration (80 chunks), heavy (high qtile) first:
//   idx5<32: q=31-(idx5>>2), c=idx5&3 | idx5<56: t=idx5-32, q=23-t/3, c=t%3
//   idx5<72: t=idx5-56, q=15-(t>>1), c=t&1 | else: q=7-(idx5-72), c=0
//  Inner loop byte-identical to the verified R0/R4 structure.
// ---------------------------------------------------------------------------
__global__ __launch_bounds__(256) void flash_attn(const unsigned short* __restrict__ qb,
                                                  const unsigned short* __restrict__ kb,
                                                  const unsigned short* __restrict__ vt,
                                                  float* __restrict__ pO,
                                                  float* __restrict__ pL) {
    __shared__ unsigned short KtL[64 * 32];   // [key][32 halves, chunk-swizzled]
    __shared__ unsigned short VtL[32 * 64];   // [d][64 halves, chunk-swizzled]
    __shared__ unsigned short Pl[4 * 16 * 64];

    const int idx5 = blockIdx.x >> 5;         // 0..79, heavy first
    const int bh   = blockIdx.x & 31;
    int qtile, cchunk;
    if (idx5 < 32)      { qtile = 31 - (idx5 >> 2); cchunk = idx5 & 3; }
    else if (idx5 < 56) { int t = idx5 - 32; int d3 = t / 3; qtile = 23 - d3; cchunk = t - d3 * 3; }
    else if (idx5 < 72) { int t = idx5 - 56; qtile = 15 - (t >> 1); cchunk = t & 1; }
    else                { qtile = 7 - (idx5 - 72); cchunk = 0; }
    const int kt0 = cchunk * 8;
    const int ktN = min(kt0 + 8, qtile + 1);

    const int b = bh >> 4, h = bh & 15;
    const int tid  = threadIdx.x;
    const int wid  = tid >> 6;
    const int lane = tid & 63;
    const int c    = lane & 15;
    const int quad = lane >> 4;

    const int q0w = qtile * 64 + wid * 16;
    const int sK = (c & 3) ^ ((c >> 2) & 3);   // K chunk swizzle (key = j*16+c)
    const int sP = c & 7;                      // P/V chunk swizzle

    short8 qf = *(const short8*)(qb + ((size_t)(b * T_SEQ + q0w + c)) * 512 + h * HEAD_DIM + quad * 8);

    f32x4 accO[2];
    accO[0] = (f32x4)0.f; accO[1] = (f32x4)0.f;
    float l_r[4] = {0.f, 0.f, 0.f, 0.f};

    unsigned short* plw = &Pl[wid * 16 * 64];

    // staging coordinates (match verified gld_lds16 lane-contiguous mapping)
    const int krow = tid >> 2, kch = tid & 3;
    const int vd   = tid >> 3, vch = tid & 7;
    const unsigned short* kbase = kb + (size_t)bh * 2048 * 32 + (size_t)krow * 32 + kch * 8;
    const unsigned short* vbase = vt + ((size_t)(bh * 32 + vd)) * 2048 + vch * 8;

    uint4 kreg = *(const uint4*)(kbase + (size_t)kt0 * 64 * 32);
    uint4 vreg = *(const uint4*)(vbase + (size_t)kt0 * 64);

    for (int kt = kt0; kt < ktN; ++kt) {
        __syncthreads();                    // prior compute done reading LDS
        *(uint4*)&KtL[tid * 8] = kreg;      // regs landed ~1 full iter ago
        *(uint4*)&VtL[tid * 8] = vreg;
        __syncthreads();                    // staging visible

        if (kt + 1 < ktN) {                 // prefetch next tile into regs
            kreg = *(const uint4*)(kbase + (size_t)(kt + 1) * 64 * 32);
            vreg = *(const uint4*)(vbase + (kt + 1) * 64);
        }

        // --- S = Q.K^T ---
        f32x4 sv[4];
#pragma unroll
        for (int j = 0; j < 4; ++j) {
            short8 kf = *(const short8*)&KtL[(j * 16 + c) * 32 + ((quad ^ sK) << 3)];
            f32x4 z = (f32x4)0.f;
            sv[j] = __builtin_amdgcn_mfma_f32_16x16x32_bf16(qf, kf, z, 0, 0, 0);
        }

        if (kt == qtile) {
#pragma unroll
            for (int j = 0; j < 4; ++j)
#pragma unroll
                for (int r = 0; r < 4; ++r)
                    if (j * 16 + c > wid * 16 + quad * 4 + r) sv[j][r] = -30000.f;
        }

        // --- static softmax base-2; P -> LDS (chunk-swizzled) ---
#pragma unroll
        for (int j = 0; j < 4; ++j)
#pragma unroll
            for (int r = 0; r < 4; ++r) {
                float p = exp2f(sv[j][r]);
                l_r[r] += p;
                int row = quad * 4 + r;
                plw[row * 64 + (((j * 2 + (c >> 3)) ^ (row & 7)) << 3) + (c & 7)] = f2bf_trunc(p);
            }

        // --- PV ---
#pragma unroll
        for (int kk = 0; kk < 2; ++kk) {
            short8 pf = *(const short8*)&plw[c * 64 + (((kk * 4 + quad) ^ sP) << 3)];
#pragma unroll
            for (int ns = 0; ns < 2; ++ns) {
                short8 vf = *(const short8*)&VtL[(ns * 16 + c) * 64 + (((kk * 4 + quad) ^ sP) << 3)];
                accO[ns] = __builtin_amdgcn_mfma_f32_16x16x32_bf16(pf, vf, accO[ns], 0, 0, 0);
            }
        }
    }

    // --- epilogue: reduce l over c-lanes, write f32 partials ---
    const size_t slot = ((size_t)(bh * 32 + qtile)) * 4 + cchunk;
#pragma unroll
    for (int r = 0; r < 4; ++r) {
        float lr = l_r[r];
        lr += __shfl_xor(lr, 1);
        lr += __shfl_xor(lr, 2);
        lr += __shfl_xor(lr, 4);
        lr += __shfl_xor(lr, 8);
        int qrl = wid * 16 + quad * 4 + r;         // 0..63 within tile
        if (c == 0) pL[slot * 64 + qrl] = lr;
        float* po = pO + slot * 2048 + (size_t)qrl * 32;
        po[c]      = accO[0][r];
        po[16 + c] = accO[1][r];
    }
}

// Merge split-K partials: O = sum(Oc) / sum(lc) -> bf16 ob.
// 32 bh x 32 q x 64 rows x 8 d-groups = 524288 threads.
__global__ __launch_bounds__(256) void combine_split(const float* __restrict__ pO,
                                                     const float* __restrict__ pL,
                                                     unsigned short* __restrict__ ob) {
    int idx = blockIdx.x * 256 + threadIdx.x;
    int d4  = (idx & 7) * 4;
    int rid = idx >> 3;            // [bh][q][row]
    int bh  = rid >> 11;
    int rem = rid & 2047;
    int q   = rem >> 6;
    int row = rem & 63;
    int nc  = (q >> 3) + 1;        // chunks for this qtile (1..4)
    size_t slot0 = ((size_t)(bh * 32 + q)) * 4;
    float4 o = make_float4(0.f, 0.f, 0.f, 0.f);
    float l = 0.f;
    for (int cc = 0; cc < nc; ++cc) {
        float4 p = *(const float4*)(pO + (slot0 + cc) * 2048 + (size_t)row * 32 + d4);
        o.x += p.x; o.y += p.y; o.z += p.z; o.w += p.w;
        l += pL[(slot0 + cc) * 64 + row];
    }
    float inv = 1.f / l;
    int t = q * 64 + row;
    int b = bh >> 4, h = bh & 15;
    ushort4 st;
    st.x = f2bf(o.x * inv); st.y = f2bf(o.y * inv);
    st.z = f2bf(o.z * inv); st.w = f2bf(o.w * inv);
    *(ushort4*)(ob + ((size_t)(b * T_SEQ + t)) * 512 + h * HEAD_DIM + d4) = st;
}

extern "C" void kernel_launch(void* const* d_in, const int* in_sizes, int n_in,
                              void* d_out, int out_size, void* d_ws, size_t ws_size,
                              hipStream_t stream) {
    const float* x     = (const float*)d_in[0];
    const float* w_qkv = (const float*)d_in[1];
    const float* w_o   = (const float*)d_in[2];
    float* out = (float*)d_out;

    // workspace (ushorts): qb | kb | vt | xb | wqb | wob | ob, then f32 pO | pL
    unsigned short* qb  = (unsigned short*)d_ws;
    unsigned short* kb  = qb  + (size_t)NTOK * D_MODEL;
    unsigned short* vt  = kb  + (size_t)32 * 2048 * 32;
    unsigned short* xb  = vt  + (size_t)32 * 32 * 2048;
    unsigned short* wqb = xb  + (size_t)NTOK * D_MODEL;
    unsigned short* wob = wqb + (size_t)QKV_DIM * D_MODEL;
    unsigned short* ob  = wob + (size_t)D_MODEL * D_MODEL;
    float*          pO  = (float*)(ob + (size_t)NTOK * D_MODEL);   // 32*32*4 slots x 64 x 32
    float*          pL  = pO + (size_t)32 * 32 * 4 * 64 * 32;      // 32*32*4 slots x 64

    {
        int total = N4_X + N4_WQ + N4_WO;
        cvt_all<<<(total + 255) / 256, 256, 0, stream>>>(x, w_qkv, w_o, xb, wqb, wob);
    }
    // QKV projection + fused RoPE/scale; Q->qb, K->kb (swizzled), V->vt (swizzled)
    {
        dim3 grid(QKV_DIM / 64, NTOK / 128);   // (24, 32) = 768 blocks
        gemm_nt<128, D_MODEL, D_MODEL, true, true><<<grid, 256, 0, stream>>>(xb, wqb, qb, kb, vt);
    }
    // Flash split-K: 2560 blocks (80 chunks x 32 bh), heavy chunks first
    {
        flash_attn<<<2560, 256, 0, stream>>>(qb, kb, vt, pO, pL);
    }
    // Combine partials -> ob
    {
        combine_split<<<524288 / 256, 256, 0, stream>>>(pO, pL, ob);
    }
    // Output projection (A = attn in ob, lda 512) -> fp32 out
    {
        dim3 grid(D_MODEL / 64, NTOK / 64);   // (8, 64) = 512 blocks
        gemm_nt<64, D_MODEL, D_MODEL, false, false><<<grid, 256, 0, stream>>>(ob, wob, out, nullptr, nullptr);
    }
}

// Round 7
// 119.488 us; speedup vs baseline: 1.5282x; 1.0845x over previous
//
#include <hip/hip_runtime.h>
#include <hip/hip_bf16.h>
#include <math.h>

#define D_MODEL 512
#define N_HEADS 16
#define HEAD_DIM 32
#define T_SEQ 2048
#define B_SZ 2
#define NTOK (B_SZ * T_SEQ)        // 4096
#define QKV_DIM (3 * D_MODEL)      // 1536

typedef short short8 __attribute__((ext_vector_type(8)));
typedef float f32x4  __attribute__((ext_vector_type(4)));

__device__ __forceinline__ float bf2f(unsigned int u16) {
    union { unsigned int i; float f; } v;
    v.i = u16 << 16;
    return v.f;
}

__device__ __forceinline__ unsigned short f2bf(float f) {   // RNE
    union { float f; unsigned int i; } v;
    v.f = f;
    unsigned int lsb = (v.i >> 16) & 1u;
    v.i += 0x7fffu + lsb;
    return (unsigned short)(v.i >> 16);
}

__device__ __forceinline__ unsigned int f2bf_tru32(float f) {  // bf16 in low 16, f >= 0
    union { float f; unsigned int i; } v;
    v.f = f;
    return v.i >> 16;
}

__device__ __forceinline__ void gld_lds16(const void* g, void* l) {
    __builtin_amdgcn_global_load_lds(
        (const __attribute__((address_space(1))) void*)g,
        (__attribute__((address_space(3))) void*)l, 16, 0, 0);
}

// single fused fp32->bf16 convert for x | w_qkv | w_o (float4 granules)
#define N4_X   (NTOK * D_MODEL / 4)            // 524288
#define N4_WQ  (QKV_DIM * D_MODEL / 4)         // 196608
#define N4_WO  (D_MODEL * D_MODEL / 4)         // 65536
__global__ __launch_bounds__(256) void cvt_all(const float* __restrict__ x,
                                               const float* __restrict__ wq,
                                               const float* __restrict__ wo,
                                               unsigned short* __restrict__ xb,
                                               unsigned short* __restrict__ wqb,
                                               unsigned short* __restrict__ wob) {
    int i = blockIdx.x * 256 + threadIdx.x;
    const float* in;
    unsigned short* out;
    int k;
    if (i < N4_X)                { in = x;  out = xb;  k = i; }
    else if (i < N4_X + N4_WQ)   { in = wq; out = wqb; k = i - N4_X; }
    else if (i < N4_X + N4_WQ + N4_WO) { in = wo; out = wob; k = i - N4_X - N4_WQ; }
    else return;
    float4 v = ((const float4*)in)[k];
    ushort4 o;
    o.x = f2bf(v.x); o.y = f2bf(v.y); o.z = f2bf(v.z); o.w = f2bf(v.w);
    ((ushort4*)out)[k] = o;
}

// ---------------------------------------------------------------------------
// MT x 64 tile MFMA NT-GEMM (verified R0 structure, exact).
// ---------------------------------------------------------------------------
#define LOG2_10000_D16 0.8304820237218405f
#define QSCALE_LOG2 0.2550348788f   // (1/sqrt(32)) * log2(e)

template<int MT, int LDA, int LDC, bool OUT_BF16, bool ROPE>
__global__ __launch_bounds__(256) void gemm_nt(const unsigned short* __restrict__ A,
                                               const unsigned short* __restrict__ B,
                                               void* __restrict__ Cout,
                                               unsigned short* __restrict__ kb,
                                               unsigned short* __restrict__ vt) {
    __shared__ unsigned short Als[MT * 64];
    __shared__ unsigned short Bls[64 * 64];

    const int tid = threadIdx.x;
    const int m0 = blockIdx.y * MT;
    const int n0 = blockIdx.x * 64;

    const int wid  = tid >> 6;
    const int lane = tid & 63;
    const int c    = lane & 15;
    const int quad = lane >> 4;
    const int wm = (wid >> 1) * (MT / 2);
    const int wn = (wid & 1) * 32;
    const int MI = MT / 32;

    f32x4 acc[MI][2];
#pragma unroll
    for (int i = 0; i < MI; ++i)
#pragma unroll
        for (int j = 0; j < 2; ++j) acc[i][j] = (f32x4)0.f;

    const int srow = wid * 8 + (lane >> 3);
    const int schk = lane & 7;

    for (int k0 = 0; k0 < 512; k0 += 64) {
#pragma unroll
        for (int it = 0; it < MT / 32; ++it) {
            const unsigned short* g = A + (size_t)(m0 + it * 32 + srow) * LDA + k0 + schk * 8;
            gld_lds16(g, &Als[(it * 32 + srow) * 64 + schk * 8]);
        }
#pragma unroll
        for (int it = 0; it < 2; ++it) {
            const unsigned short* g = B + (size_t)(n0 + it * 32 + srow) * 512 + k0 + schk * 8;
            gld_lds16(g, &Bls[(it * 32 + srow) * 64 + schk * 8]);
        }
        __syncthreads();

#pragma unroll
        for (int kk = 0; kk < 2; ++kk) {
            short8 af[MI], bfr[2];
#pragma unroll
            for (int i = 0; i < MI; ++i)
                af[i] = *(const short8*)&Als[(wm + i * 16 + c) * 64 + kk * 32 + quad * 8];
#pragma unroll
            for (int j = 0; j < 2; ++j)
                bfr[j] = *(const short8*)&Bls[(wn + j * 16 + c) * 64 + kk * 32 + quad * 8];
#pragma unroll
            for (int i = 0; i < MI; ++i)
#pragma unroll
                for (int j = 0; j < 2; ++j)
                    acc[i][j] = __builtin_amdgcn_mfma_f32_16x16x32_bf16(af[i], bfr[j], acc[i][j], 0, 0, 0);
        }
        __syncthreads();
    }

    if (ROPE) {
        const int sec = n0 >> 9;     // 0 = Q, 1 = K, 2 = V
        if (sec == 0) {
            const float invf = exp2f(-LOG2_10000_D16 * (float)c);
#pragma unroll
            for (int i = 0; i < MI; ++i)
#pragma unroll
                for (int r = 0; r < 4; ++r) {
                    int t = (m0 + wm + i * 16 + quad * 4 + r) & (T_SEQ - 1);
                    float ss, cc;
                    sincosf((float)t * invf, &ss, &cc);
                    float e0 = acc[i][0][r], e1 = acc[i][1][r];
                    acc[i][0][r] = (e0 * cc - e1 * ss) * QSCALE_LOG2;
                    acc[i][1][r] = (e1 * cc + e0 * ss) * QSCALE_LOG2;
                }
            // falls through to generic bf16 writer -> qb (LDC = 512)
        } else if (sec == 1) {
            const float invf = exp2f(-LOG2_10000_D16 * (float)c);
            const int head = ((n0 - 512) + wn) >> 5;
#pragma unroll
            for (int i = 0; i < MI; ++i)
#pragma unroll
                for (int r = 0; r < 4; ++r) {
                    int mm = m0 + wm + i * 16 + quad * 4 + r;
                    int t = mm & (T_SEQ - 1);
                    float ss, cc;
                    sincosf((float)t * invf, &ss, &cc);
                    float e0 = acc[i][0][r], e1 = acc[i][1][r];
                    float k0v = e0 * cc - e1 * ss;     // d = c
                    float k1v = e1 * cc + e0 * ss;     // d = 16 + c
                    int bh = (mm >> 11) * 16 + head;
                    int s = (t & 3) ^ ((t >> 2) & 3);
                    unsigned short* row = kb + ((size_t)(bh * 2048 + t)) * 32;
                    row[((((c) >> 3) ^ s) << 3) + (c & 7)]        = f2bf(k0v);
                    row[((((16 + c) >> 3) ^ s) << 3) + (c & 7)]   = f2bf(k1v);
                }
            return;
        } else {
            // V -> vt[bh][d][t] with chunk swizzle; 4 acc rows = 4 consec t
#pragma unroll
            for (int i = 0; i < MI; ++i)
#pragma unroll
                for (int j = 0; j < 2; ++j) {
                    int nl = n0 - 1024 + wn + j * 16;
                    int head = nl >> 5;
                    int d = (nl & 16) + c;
                    int mm = m0 + wm + i * 16 + quad * 4;
                    int bI = mm >> 11;
                    int pos = mm & (T_SEQ - 1);
                    int phys = ((pos >> 3) & 7) ^ (d & 7);
                    size_t base = ((size_t)((bI * 16 + head) * 32 + d)) * 2048
                                  + (pos & ~63) + (phys << 3) + (pos & 7);
                    ushort4 st;
                    st.x = f2bf(acc[i][j][0]); st.y = f2bf(acc[i][j][1]);
                    st.z = f2bf(acc[i][j][2]); st.w = f2bf(acc[i][j][3]);
                    *(ushort4*)(vt + base) = st;
                }
            return;
        }
    }

    if (OUT_BF16) {
        unsigned short* Cb = (unsigned short*)Cout;
#pragma unroll
        for (int i = 0; i < MI; ++i)
#pragma unroll
            for (int j = 0; j < 2; ++j)
#pragma unroll
                for (int r = 0; r < 4; ++r) {
                    int mm = m0 + wm + i * 16 + quad * 4 + r;
                    int nn = n0 + wn + j * 16 + c;
                    Cb[(size_t)mm * LDC + nn] = f2bf(acc[i][j][r]);
                }
    } else {
        float* Cf = (float*)Cout;
#pragma unroll
        for (int i = 0; i < MI; ++i)
#pragma unroll
            for (int j = 0; j < 2; ++j)
#pragma unroll
                for (int r = 0; r < 4; ++r) {
                    int mm = m0 + wm + i * 16 + quad * 4 + r;
                    int nn = n0 + wn + j * 16 + c;
                    Cf[(size_t)mm * LDC + nn] = acc[i][j][r];
                }
    }
}

// ---------------------------------------------------------------------------
// Flash attention v10: swapped QK^T -> vectorized P path.
//  Diagnosis: LDS pipe per CU is the binding resource (~237 cyc/wave-iter,
//  16 scalar ds_write_b16 P-stores = 93 of them). Fix:
//   * sv[j] = mfma(kf, qf): S[key=j*16+quad*4+r][q=c] — thread holds 4
//     CONSECUTIVE keys per j (A/B fragments have identical lane layouts
//     for 16x16x32, so operand swap needs no reloads).
//   * P stored [q][key] rows padded to 72 ushorts (144B): ushort idx = key.
//     Write = 4 x ds_write_b64 (was 16 x ds_write_b16); PV read = b128 at
//     &plw[c*72 + kk*32 + quad*8] (16B-aligned, bank-uniform).
//   * mask: j*16+quad*4+r > wid*16+c on the diagonal tile.
//   * l: per-thread partial for q=c; epilogue reduces via shfl_xor(16,32)
//     then 4 computed shfl to redistribute to q=quad*4+r rows.
//  Everything else (staging, 2-barrier loop, grid 1024 heavy-first, K/V
//  layouts/swizzles) byte-identical to the best-measured R0 structure.
// ---------------------------------------------------------------------------
__global__ __launch_bounds__(256) void flash_attn(const unsigned short* __restrict__ qb,
                                                  const unsigned short* __restrict__ kb,
                                                  const unsigned short* __restrict__ vt,
                                                  unsigned short* __restrict__ ob) {
    __shared__ unsigned short KtL[64 * 32];   // [key][32 halves, chunk-swizzled]
    __shared__ unsigned short VtL[32 * 64];   // [d][64 halves, chunk-swizzled]
    __shared__ unsigned short Pl[4 * 16 * 72]; // per-wave 16 q-rows x 72 (64 keys + pad)

    const int idx   = blockIdx.x;             // 0..1023
    const int qtile = 31 - (idx >> 5);        // globally heavy first
    const int bh    = idx & 31;
    const int b = bh >> 4, h = bh & 15;
    const int tid  = threadIdx.x;
    const int wid  = tid >> 6;
    const int lane = tid & 63;
    const int c    = lane & 15;
    const int quad = lane >> 4;

    const int q0w = qtile * 64 + wid * 16;
    const int sK = (c & 3) ^ ((c >> 2) & 3);   // K chunk swizzle (key = j*16+c)
    const int sP = c & 7;                      // V chunk swizzle

    short8 qf = *(const short8*)(qb + ((size_t)(b * T_SEQ + q0w + c)) * 512 + h * HEAD_DIM + quad * 8);

    f32x4 accO[2];
    accO[0] = (f32x4)0.f; accO[1] = (f32x4)0.f;
    float l_part = 0.f;                        // partial denom for q = q0w + c

    unsigned short* plw = &Pl[wid * 16 * 72];

    // staging coordinates (match verified gld_lds16 lane-contiguous mapping)
    const int krow = tid >> 2, kch = tid & 3;
    const int vd   = tid >> 3, vch = tid & 7;
    const unsigned short* kbase = kb + (size_t)bh * 2048 * 32 + (size_t)krow * 32 + kch * 8;
    const unsigned short* vbase = vt + ((size_t)(bh * 32 + vd)) * 2048 + vch * 8;

    uint4 kreg = *(const uint4*)(kbase);
    uint4 vreg = *(const uint4*)(vbase);

    const int nkt = qtile + 1;
    for (int kt = 0; kt < nkt; ++kt) {
        __syncthreads();                    // prior compute done reading LDS
        *(uint4*)&KtL[tid * 8] = kreg;      // regs landed ~1 full iter ago
        *(uint4*)&VtL[tid * 8] = vreg;
        __syncthreads();                    // staging visible

        if (kt + 1 < nkt) {                 // prefetch next tile into regs
            kreg = *(const uint4*)(kbase + (size_t)(kt + 1) * 64 * 32);
            vreg = *(const uint4*)(vbase + (kt + 1) * 64);
        }

        // --- S^T = K.Q^T : sv[j][r] = S[key=j*16+quad*4+r][q=q0w+c] ---
        f32x4 sv[4];
#pragma unroll
        for (int j = 0; j < 4; ++j) {
            short8 kf = *(const short8*)&KtL[(j * 16 + c) * 32 + ((quad ^ sK) << 3)];
            f32x4 z = (f32x4)0.f;
            sv[j] = __builtin_amdgcn_mfma_f32_16x16x32_bf16(kf, qf, z, 0, 0, 0);
        }

        if (kt == qtile) {                  // causal: mask key > q
#pragma unroll
            for (int j = 0; j < 4; ++j)
#pragma unroll
                for (int r = 0; r < 4; ++r)
                    if (j * 16 + quad * 4 + r > wid * 16 + c) sv[j][r] = -30000.f;
        }

        // --- static softmax base-2; P -> LDS rows [q][key], b64 writes ---
#pragma unroll
        for (int j = 0; j < 4; ++j) {
            float p0 = exp2f(sv[j][0]);
            float p1 = exp2f(sv[j][1]);
            float p2 = exp2f(sv[j][2]);
            float p3 = exp2f(sv[j][3]);
            l_part += (p0 + p1) + (p2 + p3);
            unsigned int w0 = f2bf_tru32(p0) | (f2bf_tru32(p1) << 16);
            unsigned int w1 = f2bf_tru32(p2) | (f2bf_tru32(p3) << 16);
            uint2 w = make_uint2(w0, w1);
            *(uint2*)&plw[c * 72 + j * 16 + quad * 4] = w;   // ushort idx = key
        }

        // --- PV : A = P[q][k] (row q=c frag), B = V ---
#pragma unroll
        for (int kk = 0; kk < 2; ++kk) {
            short8 pf = *(const short8*)&plw[c * 72 + kk * 32 + quad * 8];
#pragma unroll
            for (int ns = 0; ns < 2; ++ns) {
                short8 vf = *(const short8*)&VtL[(ns * 16 + c) * 64 + (((kk * 4 + quad) ^ sP) << 3)];
                accO[ns] = __builtin_amdgcn_mfma_f32_16x16x32_bf16(pf, vf, accO[ns], 0, 0, 0);
            }
        }
    }

    // --- epilogue: l lives per q=c; reduce across quads, redistribute ---
    float lr = l_part;
    lr += __shfl_xor(lr, 16);
    lr += __shfl_xor(lr, 32);               // lane (c,quad) holds l[q0w + c]
#pragma unroll
    for (int r = 0; r < 4; ++r) {
        float lq = __shfl(lr, quad * 4 + r);    // l for q-local = quad*4+r
        float inv = 1.f / lq;
        int qg = q0w + quad * 4 + r;
        unsigned short* op = ob + ((size_t)(b * T_SEQ + qg)) * 512 + h * HEAD_DIM;
#pragma unroll
        for (int ns = 0; ns < 2; ++ns)
            op[ns * 16 + c] = f2bf(accO[ns][r] * inv);
    }
}

extern "C" void kernel_launch(void* const* d_in, const int* in_sizes, int n_in,
                              void* d_out, int out_size, void* d_ws, size_t ws_size,
                              hipStream_t stream) {
    const float* x     = (const float*)d_in[0];
    const float* w_qkv = (const float*)d_in[1];
    const float* w_o   = (const float*)d_in[2];
    float* out = (float*)d_out;

    // workspace (ushorts): qb 4MB | kb 4 | vt 4 | xb 4 | wqb 1.5 | wob 0.5 | ob 4
    unsigned short* qb  = (unsigned short*)d_ws;
    unsigned short* kb  = qb  + (size_t)NTOK * D_MODEL;
    unsigned short* vt  = kb  + (size_t)32 * 2048 * 32;
    unsigned short* xb  = vt  + (size_t)32 * 32 * 2048;
    unsigned short* wqb = xb  + (size_t)NTOK * D_MODEL;
    unsigned short* wob = wqb + (size_t)QKV_DIM * D_MODEL;
    unsigned short* ob  = wob + (size_t)D_MODEL * D_MODEL;

    {
        int total = N4_X + N4_WQ + N4_WO;
        cvt_all<<<(total + 255) / 256, 256, 0, stream>>>(x, w_qkv, w_o, xb, wqb, wob);
    }
    // QKV projection + fused RoPE/scale; Q->qb, K->kb (swizzled), V->vt (swizzled)
    {
        dim3 grid(QKV_DIM / 64, NTOK / 128);   // (24, 32) = 768 blocks
        gemm_nt<128, D_MODEL, D_MODEL, true, true><<<grid, 256, 0, stream>>>(xb, wqb, qb, kb, vt);
    }
    // Flash: 1024 blocks, globally heavy-first
    {
        flash_attn<<<1024, 256, 0, stream>>>(qb, kb, vt, ob);
    }
    // Output projection (A = attn in ob, lda 512) -> fp32 out
    {
        dim3 grid(D_MODEL / 64, NTOK / 64);   // (8, 64) = 512 blocks
        gemm_nt<64, D_MODEL, D_MODEL, false, false><<<grid, 256, 0, stream>>>(ob, wob, out, nullptr, nullptr);
    }
}